// Round 11
// baseline (5471.207 us; speedup 1.0000x reference)
//
#include <hip/hip_runtime.h>
#include <hip/hip_bf16.h>

// DGMNet: B=65536, IN=16, H=1024, L=4, OUT=1. All I/O fp32, bf16 MFMA inside.
// Round-11: r10 zero-stream persistent kernel + small-budget soft barriers.
// Unified model from r6-r10 PMC: live set Wz+Wg+XT = 4.25MB > 4MB L2 (both
// tables live due to CU desync) -> ~7.5% miss of ALL L2 flow -> ~4GB via the
// slow TCC-EA path. r8 proved the SYSTEM-scope barrier converges (23us wait
// << budget); r10 proved streams are gone. Combined: phase-align sweeps so
// only ONE 2MiB table is live at a time (2.25MB << 4MB). Barrier = bounded
// 32-poll spin (~15us cap, retried each time, deadlock-impossible).

typedef float f32x4 __attribute__((ext_vector_type(4)));
typedef __bf16 bf16x8 __attribute__((ext_vector_type(8)));

#define MFMA16 __builtin_amdgcn_mfma_f32_16x16x32_bf16

// ---------- ws layout ----------
#define WS_WZ   0u
#define WS_WG   (2u << 20)
#define WS_XT   (4u << 20)
#define WS_BIAS ((4u << 20) + 6u * 65536u)
#define WS_CTR  (WS_BIAS + 24576u)            // barrier counter (4B)
#define WS_NEED ((size_t)8 << 20)

static __device__ __forceinline__ unsigned short f2bf(float f) {
    __hip_bfloat16 h = __float2bfloat16(f);
    union { __hip_bfloat16 h; unsigned short u; } c; c.h = h; return c.u;
}
static __device__ __forceinline__ float bf2f(unsigned short u) {
    union { unsigned int u; float f; } c; c.u = ((unsigned int)u) << 16; return c.f;
}
static __device__ __forceinline__ float fast_tanh(float x) {
    float e = __expf(2.0f * x);
    return 1.0f - 2.0f * __builtin_amdgcn_rcpf(e + 1.0f);
}
// LDS swizzle for [32][1024] bf16 tile (G4 bank-conflict fix)
static __device__ __forceinline__ unsigned int swoff(int row, int kelem) {
    unsigned int a = (unsigned int)(row * 2048 + kelem * 2);
    return a ^ (unsigned int)((row & 7) << 4);
}

// Soft grid barrier: timing-only (no data crosses WGs). AGENT-scope add,
// SYSTEM-scope poll (reads coherence point; r8-proven to converge). Bounded
// 32-poll spin (~15us) -> deadlock-impossible; retried at every barrier.
static __device__ __forceinline__ void soft_bar(unsigned int* ctr,
                                                unsigned int target, int tid) {
    __syncthreads();
    if (tid == 0) {
        __hip_atomic_fetch_add(ctr, 1u, __ATOMIC_RELAXED, __HIP_MEMORY_SCOPE_AGENT);
        int polls = 0;
        for (;;) {
            unsigned int v = __hip_atomic_load(ctr, __ATOMIC_RELAXED,
                                               __HIP_MEMORY_SCOPE_SYSTEM);
            if (v >= target) break;
            if (++polls >= 32) break;          // ~15us cap
            __builtin_amdgcn_s_sleep(8);
        }
    }
    __syncthreads();
}

// ---------------- prep kernels ----------------
__global__ void prep_big(const float* __restrict__ Wz, const float* __restrict__ Wg,
                         char* __restrict__ ws) {
    int bid = blockIdx.x;                 // 4096 blocks: mat(2) x ks(32) x cf(64)
    int mat = bid >> 11, rem = bid & 2047;
    int ks = rem >> 6, cf = rem & 63;
    const float* src = mat ? Wg : Wz;
    char* dst = ws + ((size_t)mat << 21) + ((size_t)(ks * 64 + cf) << 10);
    int l = threadIdx.x;
    int col = cf * 16 + (l & 15);
    int kb  = ks * 32 + ((l >> 4) << 3);
    unsigned short* d = (unsigned short*)(dst + l * 16);
    #pragma unroll
    for (int j = 0; j < 8; ++j) d[j] = f2bf(src[col * 1024 + kb + j]);
}

__global__ void prep_x(const float* __restrict__ Uz, const float* __restrict__ Ur,
                       const float* __restrict__ Uh, const float* __restrict__ Ug,
                       const float* __restrict__ Sw, char* __restrict__ xt) {
    int bid = blockIdx.x;                 // 384 blocks: gate(6) x cf(64)
    int g_ = bid >> 6, cf = bid & 63;
    int l = threadIdx.x;
    int col = cf * 16 + (l & 15);
    int kb  = (l >> 4) << 3;
    unsigned short* d = (unsigned short*)(xt + ((size_t)(g_ * 64 + cf) << 10) + l * 16);
    #pragma unroll
    for (int j = 0; j < 8; ++j) {
        int k = kb + j;
        float v = 0.0f;
        if (k < 16) {
            int idx = col * 16 + k;
            switch (g_) {
                case 0: v = Uz[idx]; break;
                case 1: v = Ur[idx]; break;
                case 2: v = Uh[idx]; break;
                case 3: v = Ug[idx]; break;
                case 4: v = Ur[idx] - Ug[idx]; break;
                case 5: v = Sw[idx]; break;
            }
        }
        d[j] = f2bf(v);
    }
}

__global__ void prep_bias(const float* __restrict__ Uz_b, const float* __restrict__ Wz_b,
                          const float* __restrict__ Ur_b, const float* __restrict__ Uh_b,
                          const float* __restrict__ Ug_b, const float* __restrict__ Wg_b,
                          const float* __restrict__ Sw_b, float* __restrict__ dst,
                          unsigned int* ctr) {
    int i = blockIdx.x * 256 + threadIdx.x;
    dst[i]        = Uz_b[i] + Wz_b[i];        // bz
    dst[1024 + i] = Ur_b[i] + Wg_b[i];        // br
    dst[2048 + i] = Uh_b[i] + Wg_b[i];        // bh
    dst[3072 + i] = Ug_b[i] + Wg_b[i];        // bg
    dst[4096 + i] = Sw_b[i];                  // bs
    if (i == 0)
        __hip_atomic_store(ctr, 0u, __ATOMIC_RELAXED, __HIP_MEMORY_SCOPE_SYSTEM);
}

// ---------------- device helpers (16 waves, M=32, 64 cols/wave) ----------------
static __device__ __forceinline__ void stage_xb(const float* __restrict__ x,
                                                unsigned short* xb, int t, int tid) {
    int r = tid >> 5, c = tid & 31;           // 32x32, one elem per thread
    float v = (c < 16) ? x[(size_t)(t * 32 + r) * 16 + c] : 0.0f;
    xb[tid] = f2bf(v);
}

static __device__ __forceinline__ void mmx32(f32x4 (&acc)[2][4], const char* __restrict__ xtab,
                                             const unsigned short* xb, int lane, int wv) {
    const int c15 = lane & 15, h = lane >> 4;
    bf16x8 a[2];
    #pragma unroll
    for (int rf = 0; rf < 2; ++rf)
        a[rf] = *(const bf16x8*)(xb + (c15 + 16 * rf) * 32 + h * 8);
    #pragma unroll
    for (int cf = 0; cf < 4; ++cf) {
        bf16x8 b = *(const bf16x8*)(xtab + ((wv * 4 + cf) << 10) + lane * 16);
        #pragma unroll
        for (int rf = 0; rf < 2; ++rf) acc[rf][cf] = MFMA16(a[rf], b, acc[rf][cf], 0, 0, 0);
    }
}

static __device__ __forceinline__ void mms32(f32x4 (&acc)[2][4], const char* __restrict__ stab,
                                             const char* sb, int lane, int wv) {
    const int c15 = lane & 15, h = lane >> 4;
    #pragma unroll 2
    for (int ks = 0; ks < 32; ++ks) {
        const char* bp = stab + ((size_t)(ks * 64 + wv * 4) << 10) + lane * 16;
        bf16x8 b[4];
        #pragma unroll
        for (int cf = 0; cf < 4; ++cf) b[cf] = *(const bf16x8*)(bp + (cf << 10));
        bf16x8 a[2];
        #pragma unroll
        for (int rf = 0; rf < 2; ++rf)
            a[rf] = *(const bf16x8*)(sb + swoff(c15 + 16 * rf, (ks << 5) + (h << 3)));
        #pragma unroll
        for (int cf = 0; cf < 4; ++cf)
            #pragma unroll
            for (int rf = 0; rf < 2; ++rf)
                acc[rf][cf] = MFMA16(a[rf], b[cf], acc[rf][cf], 0, 0, 0);
    }
}

#define ZERO_ACC2(acc) { _Pragma("unroll") for (int rf_ = 0; rf_ < 2; ++rf_) \
    _Pragma("unroll") for (int cf_ = 0; cf_ < 4; ++cf_) acc[rf_][cf_] = (f32x4)0.0f; }

// ---------------- the zero-stream phase-aligned persistent kernel ----------------
__global__ __launch_bounds__(1024, 4)
void mega32(const float* __restrict__ x, const char* __restrict__ ws,
            const float* __restrict__ ow, const float* __restrict__ ob,
            float* __restrict__ outp, unsigned int* ctr) {
    extern __shared__ char lds[];
    char* sbuf = lds;                                    // 64 KiB: S / SR / newS
    unsigned short* xb = (unsigned short*)(lds + 65536); // 2 KiB
    float* red = (float*)(lds + 67584);                  // 2 KiB
    unsigned int* Glds = (unsigned int*)(lds + 69632);   // 64 KiB: 16 planes x 1024
    const int tid = threadIdx.x, lane = tid & 63, wv = tid >> 6;
    const int c15 = lane & 15, h = lane >> 4;
    const int wg = blockIdx.x;

    const float* BZ = (const float*)(ws + WS_BIAS);
    const float* BR = BZ + 1024;
    const float* BH = BZ + 2048;
    const float* BG = BZ + 3072;
    const float* BS = BZ + 4096;

    unsigned int epoch = 0;                              // uniform across WGs

    #pragma clang loop unroll(disable)
    for (int rt = 0; rt < 8; ++rt) {
        const int t = rt * 256 + wg;                     // rows t*32..t*32+31
        stage_xb(x, xb, t, tid);
        __syncthreads();

        f32x4 acc[2][4];
        // ---- S1 = x @ Sw^T + bs (raw) -> sbuf (XT only, no table) ----
        ZERO_ACC2(acc);
        mmx32(acc, ws + WS_XT + 5 * 65536, xb, lane, wv);
        #pragma unroll
        for (int cf = 0; cf < 4; ++cf) {
            int col = (wv << 6) + (cf << 4) + c15;
            float b = BS[col];
            #pragma unroll
            for (int rf = 0; rf < 2; ++rf)
                #pragma unroll
                for (int r = 0; r < 4; ++r) {
                    int row = (rf << 4) + (h << 2) + r;
                    *(unsigned short*)(sbuf + swoff(row, col)) = f2bf(acc[rf][cf][r] + b);
                }
        }
        __syncthreads();

        // ---- G = tanh(ux_g + S1@Wg^T + bg) -> Glds ----
        soft_bar(ctr, 256u * (++epoch), tid);            // align Wg sweep
        ZERO_ACC2(acc);
        mmx32(acc, ws + WS_XT + 3 * 65536, xb, lane, wv);
        mms32(acc, ws + WS_WG, sbuf, lane, wv);
        #pragma unroll
        for (int cf = 0; cf < 4; ++cf) {
            int col = (wv << 6) + (cf << 4) + c15;
            float b = BG[col];
            #pragma unroll
            for (int rf = 0; rf < 2; ++rf) {
                float v0 = fast_tanh(acc[rf][cf][0] + b);
                float v1 = fast_tanh(acc[rf][cf][1] + b);
                float v2 = fast_tanh(acc[rf][cf][2] + b);
                float v3 = fast_tanh(acc[rf][cf][3] + b);
                int idx = (rf * 4 + cf) * 2;
                Glds[(idx + 0) * 1024 + tid] = (unsigned int)f2bf(v0) | ((unsigned int)f2bf(v1) << 16);
                Glds[(idx + 1) * 1024 + tid] = (unsigned int)f2bf(v2) | ((unsigned int)f2bf(v3) << 16);
            }
        }
        // Glds is same-thread write/read: no barrier needed for it.

        // ---- 4-layer recurrence, S resident in sbuf ----
        #pragma clang loop unroll(disable)
        for (int L = 0; L < 4; ++L) {
            // Z pass (Wz): ZS -> zsp regs (transient, dies at H epilogue)
            soft_bar(ctr, 256u * (++epoch), tid);        // align Wz sweep
            unsigned int zsp[16];
            ZERO_ACC2(acc);
            mmx32(acc, ws + WS_XT + 0 * 65536, xb, lane, wv);
            mms32(acc, ws + WS_WZ, sbuf, lane, wv);
            #pragma unroll
            for (int cf = 0; cf < 4; ++cf) {
                int col = (wv << 6) + (cf << 4) + c15;
                float bzl = BZ[col];
                #pragma unroll
                for (int rf = 0; rf < 2; ++rf) {
                    float v[4];
                    #pragma unroll
                    for (int r = 0; r < 4; ++r) {
                        int row = (rf << 4) + (h << 2) + r;
                        float z = fast_tanh(acc[rf][cf][r] + bzl);
                        v[r] = z * bf2f(*(const unsigned short*)(sbuf + swoff(row, col)));
                    }
                    zsp[(rf * 4 + cf) * 2 + 0] = (unsigned int)f2bf(v[0]) | ((unsigned int)f2bf(v[1]) << 16);
                    zsp[(rf * 4 + cf) * 2 + 1] = (unsigned int)f2bf(v[2]) | ((unsigned int)f2bf(v[3]) << 16);
                }
            }

            // R pass (Wg): SR -> srp regs (dies at the sbuf write below)
            soft_bar(ctr, 256u * (++epoch), tid);        // align Wg sweep (R + H)
            {
                unsigned int srp[16];
                ZERO_ACC2(acc);
                mmx32(acc, ws + WS_XT + 1 * 65536, xb, lane, wv);
                mms32(acc, ws + WS_WG, sbuf, lane, wv);
                #pragma unroll
                for (int cf = 0; cf < 4; ++cf) {
                    int col = (wv << 6) + (cf << 4) + c15;
                    float brl = BR[col];
                    #pragma unroll
                    for (int rf = 0; rf < 2; ++rf) {
                        float v[4];
                        #pragma unroll
                        for (int r = 0; r < 4; ++r) {
                            int row = (rf << 4) + (h << 2) + r;
                            float rv = fast_tanh(acc[rf][cf][r] + brl);
                            v[r] = rv * bf2f(*(const unsigned short*)(sbuf + swoff(row, col)));
                        }
                        srp[(rf * 4 + cf) * 2 + 0] = (unsigned int)f2bf(v[0]) | ((unsigned int)f2bf(v[1]) << 16);
                        srp[(rf * 4 + cf) * 2 + 1] = (unsigned int)f2bf(v[2]) | ((unsigned int)f2bf(v[3]) << 16);
                    }
                }
                __syncthreads();   // all S reads (Z + R) complete
                #pragma unroll
                for (int cf = 0; cf < 4; ++cf) {
                    int col = (wv << 6) + (cf << 4) + c15;
                    #pragma unroll
                    for (int rf = 0; rf < 2; ++rf)
                        #pragma unroll
                        for (int r = 0; r < 4; ++r) {
                            int row = (rf << 4) + (h << 2) + r;
                            unsigned short u = (unsigned short)((srp[(rf * 4 + cf) * 2 + (r >> 1)] >> ((r & 1) * 16)) & 0xffff);
                            *(unsigned short*)(sbuf + swoff(row, col)) = u;
                        }
                }
            }
            __syncthreads();   // SR ready

            // H pass (Wg, same table as R: no barrier)
            ZERO_ACC2(acc);
            mmx32(acc, ws + WS_XT + 2 * 65536, xb, lane, wv);
            mms32(acc, ws + WS_WG, sbuf, lane, wv);
            __syncthreads();   // all SR reads done before newS writes

            if (L < 3) {
                #pragma unroll
                for (int rfcf = 0; rfcf < 8; ++rfcf) {
                    unsigned int g0 = Glds[(rfcf * 2 + 0) * 1024 + tid];
                    unsigned int g1 = Glds[(rfcf * 2 + 1) * 1024 + tid];
                    int rf = rfcf >> 2, cf = rfcf & 3;
                    int col = (wv << 6) + (cf << 4) + c15;
                    float bhl = BH[col];
                    #pragma unroll
                    for (int r = 0; r < 4; ++r) {
                        int row = (rf << 4) + (h << 2) + r;
                        unsigned int gw = (r >> 1) ? g1 : g0;
                        unsigned int zw = zsp[rfcf * 2 + (r >> 1)];
                        float g  = bf2f((unsigned short)((gw >> ((r & 1) * 16)) & 0xffff));
                        float zs = bf2f((unsigned short)((zw >> ((r & 1) * 16)) & 0xffff));
                        float hv = fast_tanh(acc[rf][cf][r] + bhl);
                        float o  = (1.0f - g) * hv + zs;
                        *(unsigned short*)(sbuf + swoff(row, col)) = f2bf(fast_tanh(o));
                    }
                }
                __syncthreads();   // newS visible for next layer
            } else {
                float po[8];
                #pragma unroll
                for (int i = 0; i < 8; ++i) po[i] = 0.0f;
                #pragma unroll
                for (int rfcf = 0; rfcf < 8; ++rfcf) {
                    unsigned int g0 = Glds[(rfcf * 2 + 0) * 1024 + tid];
                    unsigned int g1 = Glds[(rfcf * 2 + 1) * 1024 + tid];
                    int rf = rfcf >> 2, cf = rfcf & 3;
                    int col = (wv << 6) + (cf << 4) + c15;
                    float bhl = BH[col];
                    float oww = ow[col];
                    #pragma unroll
                    for (int r = 0; r < 4; ++r) {
                        unsigned int gw = (r >> 1) ? g1 : g0;
                        unsigned int zw = zsp[rfcf * 2 + (r >> 1)];
                        float g  = bf2f((unsigned short)((gw >> ((r & 1) * 16)) & 0xffff));
                        float zs = bf2f((unsigned short)((zw >> ((r & 1) * 16)) & 0xffff));
                        float hv = fast_tanh(acc[rf][cf][r] + bhl);
                        po[(rf << 2) + r] += ((1.0f - g) * hv + zs) * oww;
                    }
                }
                #pragma unroll
                for (int off = 1; off < 16; off <<= 1)
                    #pragma unroll
                    for (int i = 0; i < 8; ++i) po[i] += __shfl_xor(po[i], off);
                if (c15 == 0) {
                    #pragma unroll
                    for (int rf = 0; rf < 2; ++rf)
                        #pragma unroll
                        for (int r = 0; r < 4; ++r)
                            red[wv * 32 + (rf << 4) + (h << 2) + r] = po[(rf << 2) + r];
                }
                __syncthreads();
                if (tid < 32) {
                    float s = ob[0];
                    #pragma unroll
                    for (int w = 0; w < 16; ++w) s += red[w * 32 + tid];
                    outp[t * 32 + tid] = s;
                }
                __syncthreads();   // red/sbuf free for next row-tile
            }
        }
    }
}

// ================= FALLBACK PATH: round-1 fused kernel (proven) =================

static __device__ __forceinline__ void mm_x(f32x4 acc[2][8], const char* __restrict__ xtab,
                                            const unsigned short* __restrict__ xb,
                                            int lane, int wv) {
    const int c15 = lane & 15, h = lane >> 4;
    bf16x8 a0 = *(const bf16x8*)(xb + c15 * 48 + h * 8);
    bf16x8 a1 = *(const bf16x8*)(xb + (c15 + 16) * 48 + h * 8);
    #pragma unroll
    for (int cf = 0; cf < 8; ++cf) {
        bf16x8 b = *(const bf16x8*)(xtab + ((wv * 8 + cf) << 10) + lane * 16);
        acc[0][cf] = MFMA16(a0, b, acc[0][cf], 0, 0, 0);
        acc[1][cf] = MFMA16(a1, b, acc[1][cf], 0, 0, 0);
    }
}

static __device__ __forceinline__ void mm_s(f32x4 acc[2][8], const char* __restrict__ stab,
                                            const char* __restrict__ sb, int lane, int wv) {
    const int c15 = lane & 15, h = lane >> 4;
    #pragma unroll 2
    for (int ks = 0; ks < 32; ++ks) {
        const char* bp = stab + ((size_t)(ks * 64 + wv * 8) << 10) + lane * 16;
        bf16x8 b[8];
        #pragma unroll
        for (int cf = 0; cf < 8; ++cf) b[cf] = *(const bf16x8*)(bp + (cf << 10));
        bf16x8 a0 = *(const bf16x8*)(sb + swoff(c15,      (ks << 5) + (h << 3)));
        bf16x8 a1 = *(const bf16x8*)(sb + swoff(c15 + 16, (ks << 5) + (h << 3)));
        #pragma unroll
        for (int cf = 0; cf < 8; ++cf) {
            acc[0][cf] = MFMA16(a0, b[cf], acc[0][cf], 0, 0, 0);
            acc[1][cf] = MFMA16(a1, b[cf], acc[1][cf], 0, 0, 0);
        }
    }
}

__global__ __launch_bounds__(512, 2)
void dgm_main(const float* __restrict__ x, const float* __restrict__ out_w,
              const float* __restrict__ out_b, const char* __restrict__ ws,
              float* __restrict__ out) {
    extern __shared__ char lds[];
    char* sbuf0 = lds;
    char* sbuf1 = lds + 65536;
    unsigned short* xb = (unsigned short*)(lds + 131072);
    float* red = (float*)(lds + 131072 + 3072);

    const int tid = threadIdx.x, lane = tid & 63, wv = tid >> 6;
    const int c15 = lane & 15, h = lane >> 4;
    const int t = blockIdx.x;

    const char* WZ = ws + WS_WZ;
    const char* WG = ws + WS_WG;
    const char* XT = ws + WS_XT;
    const float* BZ = (const float*)(ws + WS_BIAS);
    const float* BR = BZ + 1024;
    const float* BH = BZ + 2048;
    const float* BG = BZ + 3072;
    const float* BS = BZ + 4096;

    for (int i = tid; i < 32 * 48; i += 512) {
        int r_ = i / 48, c_ = i % 48;
        float v = (c_ < 16) ? x[(t * 32 + r_) * 16 + c_] : 0.0f;
        xb[r_ * 48 + c_] = f2bf(v);
    }
    __syncthreads();

    f32x4 acc[2][8];
    unsigned int g1m[2][8][2];
    unsigned int zs[2][8][2];
    float po[8];
    #pragma unroll
    for (int i = 0; i < 8; ++i) po[i] = 0.0f;

    #pragma unroll
    for (int rf = 0; rf < 2; ++rf)
        #pragma unroll
        for (int cf = 0; cf < 8; ++cf) acc[rf][cf] = (f32x4)0.0f;
    mm_x(acc, XT + 5 * 65536, xb, lane, wv);
    #pragma unroll
    for (int cf = 0; cf < 8; ++cf) {
        int col = (wv << 7) + (cf << 4) + c15;
        float b = BS[col];
        #pragma unroll
        for (int rf = 0; rf < 2; ++rf)
            #pragma unroll
            for (int r = 0; r < 4; ++r) {
                int row = (rf << 4) + (h << 2) + r;
                *(unsigned short*)(sbuf0 + swoff(row, col)) = f2bf(acc[rf][cf][r] + b);
            }
    }
    __syncthreads();

    {
        #pragma unroll
        for (int rf = 0; rf < 2; ++rf)
            #pragma unroll
            for (int cf = 0; cf < 8; ++cf) acc[rf][cf] = (f32x4)0.0f;
        mm_x(acc, XT + 3 * 65536, xb, lane, wv);
        mm_s(acc, WG, sbuf0, lane, wv);
        unsigned int wgx[2][8][2];
        #pragma unroll
        for (int rf = 0; rf < 2; ++rf)
            #pragma unroll
            for (int cf = 0; cf < 8; ++cf) {
                wgx[rf][cf][0] = (unsigned int)f2bf(acc[rf][cf][0]) |
                                 ((unsigned int)f2bf(acc[rf][cf][1]) << 16);
                wgx[rf][cf][1] = (unsigned int)f2bf(acc[rf][cf][2]) |
                                 ((unsigned int)f2bf(acc[rf][cf][3]) << 16);
            }
        #pragma unroll
        for (int rf = 0; rf < 2; ++rf)
            #pragma unroll
            for (int cf = 0; cf < 8; ++cf) acc[rf][cf] = (f32x4)0.0f;
        mm_x(acc, XT + 4 * 65536, xb, lane, wv);
        #pragma unroll
        for (int cf = 0; cf < 8; ++cf) {
            int col = (wv << 7) + (cf << 4) + c15;
            float brl = BR[col], bgl = BG[col];
            #pragma unroll
            for (int rf = 0; rf < 2; ++rf) {
                float g1v[4];
                #pragma unroll
                for (int r = 0; r < 4; ++r) {
                    int row = (rf << 4) + (h << 2) + r;
                    float wgv = bf2f((unsigned short)((wgx[rf][cf][r >> 1] >> ((r & 1) * 16)) & 0xffff));
                    float rv = fast_tanh(wgv + acc[rf][cf][r] + brl);
                    float s1 = bf2f(*(const unsigned short*)(sbuf0 + swoff(row, col)));
                    *(unsigned short*)(sbuf1 + swoff(row, col)) = f2bf(s1 * rv);
                    g1v[r] = 1.0f - fast_tanh(wgv + bgl);
                }
                g1m[rf][cf][0] = (unsigned int)f2bf(g1v[0]) | ((unsigned int)f2bf(g1v[1]) << 16);
                g1m[rf][cf][1] = (unsigned int)f2bf(g1v[2]) | ((unsigned int)f2bf(g1v[3]) << 16);
            }
        }
    }
    __syncthreads();

    char* cur = sbuf0;
    char* oth = sbuf1;
    #pragma clang loop unroll(disable)
    for (int L = 0; L < 4; ++L) {
        #pragma unroll
        for (int rf = 0; rf < 2; ++rf)
            #pragma unroll
            for (int cf = 0; cf < 8; ++cf) acc[rf][cf] = (f32x4)0.0f;
        mm_x(acc, XT + 0 * 65536, xb, lane, wv);
        mm_s(acc, WZ, cur, lane, wv);
        #pragma unroll
        for (int cf = 0; cf < 8; ++cf) {
            int col = (wv << 7) + (cf << 4) + c15;
            float bzl = BZ[col];
            #pragma unroll
            for (int rf = 0; rf < 2; ++rf) {
                float zv[4];
                #pragma unroll
                for (int r = 0; r < 4; ++r) {
                    int row = (rf << 4) + (h << 2) + r;
                    float z = fast_tanh(acc[rf][cf][r] + bzl);
                    float s = bf2f(*(const unsigned short*)(cur + swoff(row, col)));
                    zv[r] = z * s;
                }
                zs[rf][cf][0] = (unsigned int)f2bf(zv[0]) | ((unsigned int)f2bf(zv[1]) << 16);
                zs[rf][cf][1] = (unsigned int)f2bf(zv[2]) | ((unsigned int)f2bf(zv[3]) << 16);
            }
        }
        if (L > 0) {
            #pragma unroll
            for (int rf = 0; rf < 2; ++rf)
                #pragma unroll
                for (int cf = 0; cf < 8; ++cf) acc[rf][cf] = (f32x4)0.0f;
            mm_x(acc, XT + 1 * 65536, xb, lane, wv);
            mm_s(acc, WG, cur, lane, wv);
            #pragma unroll
            for (int cf = 0; cf < 8; ++cf) {
                int col = (wv << 7) + (cf << 4) + c15;
                float brl = BR[col];
                #pragma unroll
                for (int rf = 0; rf < 2; ++rf)
                    #pragma unroll
                    for (int r = 0; r < 4; ++r) {
                        int row = (rf << 4) + (h << 2) + r;
                        float rv = fast_tanh(acc[rf][cf][r] + brl);
                        float s = bf2f(*(const unsigned short*)(cur + swoff(row, col)));
                        *(unsigned short*)(oth + swoff(row, col)) = f2bf(s * rv);
                    }
            }
        }
        __syncthreads();
        #pragma unroll
        for (int rf = 0; rf < 2; ++rf)
            #pragma unroll
            for (int cf = 0; cf < 8; ++cf) acc[rf][cf] = (f32x4)0.0f;
        mm_x(acc, XT + 2 * 65536, xb, lane, wv);
        mm_s(acc, WG, oth, lane, wv);
        __syncthreads();
        if (L < 3) {
            #pragma unroll
            for (int cf = 0; cf < 8; ++cf) {
                int col = (wv << 7) + (cf << 4) + c15;
                float bhl = BH[col];
                #pragma unroll
                for (int rf = 0; rf < 2; ++rf)
                    #pragma unroll
                    for (int r = 0; r < 4; ++r) {
                        int row = (rf << 4) + (h << 2) + r;
                        float hv = fast_tanh(acc[rf][cf][r] + bhl);
                        float g1 = bf2f((unsigned short)((g1m[rf][cf][r >> 1] >> ((r & 1) * 16)) & 0xffff));
                        float zsv = bf2f((unsigned short)((zs[rf][cf][r >> 1] >> ((r & 1) * 16)) & 0xffff));
                        float o = g1 * hv + zsv;
                        *(unsigned short*)(oth + swoff(row, col)) = f2bf(fast_tanh(o));
                    }
            }
        } else {
            #pragma unroll
            for (int cf = 0; cf < 8; ++cf) {
                int col = (wv << 7) + (cf << 4) + c15;
                float bhl = BH[col];
                float oww = out_w[col];
                #pragma unroll
                for (int rf = 0; rf < 2; ++rf)
                    #pragma unroll
                    for (int r = 0; r < 4; ++r) {
                        float hv = fast_tanh(acc[rf][cf][r] + bhl);
                        float g1 = bf2f((unsigned short)((g1m[rf][cf][r >> 1] >> ((r & 1) * 16)) & 0xffff));
                        float zsv = bf2f((unsigned short)((zs[rf][cf][r >> 1] >> ((r & 1) * 16)) & 0xffff));
                        po[(rf << 2) + r] += (g1 * hv + zsv) * oww;
                    }
            }
        }
        __syncthreads();
        char* tmp = cur; cur = oth; oth = tmp;
    }

    #pragma unroll
    for (int off = 1; off < 16; off <<= 1)
        #pragma unroll
        for (int i = 0; i < 8; ++i) po[i] += __shfl_xor(po[i], off);
    if (c15 == 0) {
        #pragma unroll
        for (int rf = 0; rf < 2; ++rf)
            #pragma unroll
            for (int r = 0; r < 4; ++r)
                red[wv * 32 + (rf << 4) + (h << 2) + r] = po[(rf << 2) + r];
    }
    __syncthreads();
    if (tid < 32) {
        float s = out_b[0];
        #pragma unroll
        for (int w = 0; w < 8; ++w) s += red[w * 32 + tid];
        out[t * 32 + tid] = s;
    }
}

// ---------------- host ----------------
extern "C" void kernel_launch(void* const* d_in, const int* in_sizes, int n_in,
                              void* d_out, int out_size, void* d_ws, size_t ws_size,
                              hipStream_t stream) {
    (void)in_sizes; (void)n_in; (void)out_size;
    const float* x    = (const float*)d_in[0];
    const float* Sw_w = (const float*)d_in[1];
    const float* Sw_b = (const float*)d_in[2];
    const float* Uz_w = (const float*)d_in[3];
    const float* Uz_b = (const float*)d_in[4];
    const float* Wz_w = (const float*)d_in[5];
    const float* Wz_b = (const float*)d_in[6];
    const float* Ug_w = (const float*)d_in[7];
    const float* Ug_b = (const float*)d_in[8];
    const float* Wg_w = (const float*)d_in[9];
    const float* Wg_b = (const float*)d_in[10];
    const float* Ur_w = (const float*)d_in[11];
    const float* Ur_b = (const float*)d_in[12];
    const float* Uh_w = (const float*)d_in[13];
    const float* Uh_b = (const float*)d_in[14];
    const float* ow   = (const float*)d_in[15];
    const float* ob   = (const float*)d_in[16];
    char* ws = (char*)d_ws;
    unsigned int* ctr = (unsigned int*)(ws + WS_CTR);

    prep_big<<<4096, 64, 0, stream>>>(Wz_w, Wg_w, ws);
    prep_x<<<384, 64, 0, stream>>>(Uz_w, Ur_w, Uh_w, Ug_w, Sw_w, ws + WS_XT);
    prep_bias<<<4, 256, 0, stream>>>(Uz_b, Wz_b, Ur_b, Uh_b, Ug_b, Wg_b, Sw_b,
                                     (float*)(ws + WS_BIAS), ctr);

    if (ws_size >= WS_NEED) {
        const int LM = 65536 + 2048 + 2048 + 65536;   // 132 KiB
        hipFuncSetAttribute(reinterpret_cast<const void*>(mega32),
                            hipFuncAttributeMaxDynamicSharedMemorySize, LM);
        mega32<<<256, 1024, LM, stream>>>(x, ws, ow, ob, (float*)d_out, ctr);
    } else {
        const int ldsBytes = 131072 + 3072 + 1024;
        hipFuncSetAttribute(reinterpret_cast<const void*>(dgm_main),
                            hipFuncAttributeMaxDynamicSharedMemorySize, ldsBytes);
        dgm_main<<<65536 / 32, 512, ldsBytes, stream>>>(x, ow, ob, ws, (float*)d_out);
    }
}

// Round 12
// 3042.108 us; speedup vs baseline: 1.7985x; 1.7985x over previous
//
#include <hip/hip_runtime.h>
#include <hip/hip_bf16.h>

// DGMNet: B=65536, IN=16, H=1024, L=4, OUT=1. All I/O fp32, bf16 MFMA inside.
// Round-12: revert to the measured optimum (round-6 persistent mega-kernel,
// 3.54 ms) + s_setprio(1) around MFMA clusters (waves free-run between
// barriers -> the regime where setprio helps). The r7-r11 exploration closed
// the books: working set Wz+Wg+XT = 4.4MB > 4MB L2 forces ~7.5% table-read
// misses; occupancy is register-capped at 4 waves/SIMD (acc 64 AGPR + 64
// VGPR = 128); all restructurings (M=32, alignment, bypass, fp8/i8) compute
// worse. This family's floor is ~3.5 ms.

typedef float f32x4 __attribute__((ext_vector_type(4)));
typedef __bf16 bf16x8 __attribute__((ext_vector_type(8)));
typedef unsigned int u32x4 __attribute__((ext_vector_type(4)));

#define MFMA16 __builtin_amdgcn_mfma_f32_16x16x32_bf16

// ---------- ws layout ----------
#define WS_WZ   0u
#define WS_WG   (2u << 20)
#define WS_XT   (4u << 20)
#define WS_BIAS ((4u << 20) + 6u * 65536u)
#define WS_GB   ((size_t)8 << 20)                    // G slots: 256 x 128KB
#define WS_ZB   (WS_GB + ((size_t)32 << 20))         // ZS slots
#define WS_NEED2 (WS_ZB + ((size_t)32 << 20))        // 72MB total

static __device__ __forceinline__ unsigned short f2bf(float f) {
    __hip_bfloat16 h = __float2bfloat16(f);
    union { __hip_bfloat16 h; unsigned short u; } c; c.h = h; return c.u;
}
static __device__ __forceinline__ float bf2f(unsigned short u) {
    union { unsigned int u; float f; } c; c.u = ((unsigned int)u) << 16; return c.f;
}
static __device__ __forceinline__ float fast_tanh(float x) {
    float e = __expf(2.0f * x);
    return 1.0f - 2.0f * __builtin_amdgcn_rcpf(e + 1.0f);
}
// LDS swizzle for [64][1024] bf16 tile (G4 bank-conflict fix)
static __device__ __forceinline__ unsigned int swoff(int row, int kelem) {
    unsigned int a = (unsigned int)(row * 2048 + kelem * 2);
    return a ^ (unsigned int)((row & 7) << 4);
}
static __device__ __forceinline__ u32x4 ntl4(const void* p) {
    return __builtin_nontemporal_load((const u32x4*)p);
}
static __device__ __forceinline__ void nts4(void* p, u32x4 v) {
    __builtin_nontemporal_store(v, (u32x4*)p);
}

// ---------------- prep kernels ----------------
__global__ void prep_big(const float* __restrict__ Wz, const float* __restrict__ Wg,
                         char* __restrict__ ws) {
    int bid = blockIdx.x;                 // 4096 blocks: mat(2) x ks(32) x cf(64)
    int mat = bid >> 11, rem = bid & 2047;
    int ks = rem >> 6, cf = rem & 63;
    const float* src = mat ? Wg : Wz;
    char* dst = ws + ((size_t)mat << 21) + ((size_t)(ks * 64 + cf) << 10);
    int l = threadIdx.x;
    int col = cf * 16 + (l & 15);
    int kb  = ks * 32 + ((l >> 4) << 3);
    unsigned short* d = (unsigned short*)(dst + l * 16);
    #pragma unroll
    for (int j = 0; j < 8; ++j) d[j] = f2bf(src[col * 1024 + kb + j]);
}

__global__ void prep_x(const float* __restrict__ Uz, const float* __restrict__ Ur,
                       const float* __restrict__ Uh, const float* __restrict__ Ug,
                       const float* __restrict__ Sw, char* __restrict__ xt) {
    int bid = blockIdx.x;                 // 384 blocks: gate(6) x cf(64)
    int g_ = bid >> 6, cf = bid & 63;
    int l = threadIdx.x;
    int col = cf * 16 + (l & 15);
    int kb  = (l >> 4) << 3;
    unsigned short* d = (unsigned short*)(xt + ((size_t)(g_ * 64 + cf) << 10) + l * 16);
    #pragma unroll
    for (int j = 0; j < 8; ++j) {
        int k = kb + j;
        float v = 0.0f;
        if (k < 16) {
            int idx = col * 16 + k;
            switch (g_) {
                case 0: v = Uz[idx]; break;
                case 1: v = Ur[idx]; break;
                case 2: v = Uh[idx]; break;
                case 3: v = Ug[idx]; break;
                case 4: v = Ur[idx] - Ug[idx]; break;
                case 5: v = Sw[idx]; break;
            }
        }
        d[j] = f2bf(v);
    }
}

__global__ void prep_bias(const float* __restrict__ Uz_b, const float* __restrict__ Wz_b,
                          const float* __restrict__ Ur_b, const float* __restrict__ Uh_b,
                          const float* __restrict__ Ug_b, const float* __restrict__ Wg_b,
                          const float* __restrict__ Sw_b, float* __restrict__ dst) {
    int i = blockIdx.x * 256 + threadIdx.x;
    dst[i]        = Uz_b[i] + Wz_b[i];        // bz
    dst[1024 + i] = Ur_b[i] + Wg_b[i];        // br
    dst[2048 + i] = Uh_b[i] + Wg_b[i];        // bh
    dst[3072 + i] = Ug_b[i] + Wg_b[i];        // bg
    dst[4096 + i] = Sw_b[i];                  // bs
}

// ---------------- shared device helpers (16-wave, M=64, full width) ----------------
static __device__ __forceinline__ void stage_xb(const float* __restrict__ x,
                                                unsigned short* xb, int t, int tid) {
    for (int i = tid; i < 64 * 32; i += 1024) {
        int r = i >> 5, c = i & 31;
        float v = (c < 16) ? x[(size_t)(t * 64 + r) * 16 + c] : 0.0f;
        xb[i] = f2bf(v);
    }
}

static __device__ __forceinline__ void mmx16(f32x4 (&acc)[4][4], const char* __restrict__ xtab,
                                             const unsigned short* xb, int lane, int wv) {
    const int c15 = lane & 15, h = lane >> 4;
    bf16x8 a[4];
    #pragma unroll
    for (int rf = 0; rf < 4; ++rf)
        a[rf] = *(const bf16x8*)(xb + (c15 + 16 * rf) * 32 + h * 8);
    __builtin_amdgcn_s_setprio(1);
    #pragma unroll
    for (int cf = 0; cf < 4; ++cf) {
        bf16x8 b = *(const bf16x8*)(xtab + ((wv * 4 + cf) << 10) + lane * 16);
        #pragma unroll
        for (int rf = 0; rf < 4; ++rf) acc[rf][cf] = MFMA16(a[rf], b, acc[rf][cf], 0, 0, 0);
    }
    __builtin_amdgcn_s_setprio(0);
}

static __device__ __forceinline__ void mms16(f32x4 (&acc)[4][4], const char* __restrict__ stab,
                                             const char* sb, int lane, int wv) {
    const int c15 = lane & 15, h = lane >> 4;
    #pragma unroll 2
    for (int ks = 0; ks < 32; ++ks) {
        const char* bp = stab + ((size_t)(ks * 64 + wv * 4) << 10) + lane * 16;
        bf16x8 b[4];
        #pragma unroll
        for (int cf = 0; cf < 4; ++cf) b[cf] = *(const bf16x8*)(bp + (cf << 10));
        bf16x8 a[4];
        #pragma unroll
        for (int rf = 0; rf < 4; ++rf)
            a[rf] = *(const bf16x8*)(sb + swoff(c15 + 16 * rf, (ks << 5) + (h << 3)));
        __builtin_amdgcn_s_setprio(1);
        #pragma unroll
        for (int cf = 0; cf < 4; ++cf)
            #pragma unroll
            for (int rf = 0; rf < 4; ++rf)
                acc[rf][cf] = MFMA16(a[rf], b[cf], acc[rf][cf], 0, 0, 0);
        __builtin_amdgcn_s_setprio(0);
    }
}

#define ZERO_ACC(acc) { _Pragma("unroll") for (int rf_ = 0; rf_ < 4; ++rf_) \
    _Pragma("unroll") for (int cf_ = 0; cf_ < 4; ++cf_) acc[rf_][cf_] = (f32x4)0.0f; }

// ---------------- the persistent mega-kernel ----------------
__global__ __launch_bounds__(1024, 4)
void mega(const float* __restrict__ x, const char* __restrict__ ws,
          const float* __restrict__ ow, const float* __restrict__ ob,
          float* __restrict__ outp, char* __restrict__ Gb, char* __restrict__ Zb) {
    extern __shared__ char lds[];
    char* sbuf = lds;                                   // 128 KiB: S / SR / newS
    unsigned short* xb = (unsigned short*)(lds + 131072); // 4 KiB
    float* red = (float*)(lds + 131072 + 4096);         // 4 KiB
    const int tid = threadIdx.x, lane = tid & 63, wv = tid >> 6;
    const int c15 = lane & 15, h = lane >> 4;
    const int wg = blockIdx.x;
    char* gslot = Gb + ((size_t)wg << 17);              // 128 KiB per WG
    char* zslot = Zb + ((size_t)wg << 17);

    const float* BZ = (const float*)(ws + WS_BIAS);
    const float* BR = BZ + 1024;
    const float* BH = BZ + 2048;
    const float* BG = BZ + 3072;
    const float* BS = BZ + 4096;

    #pragma clang loop unroll(disable)
    for (int rt = 0; rt < 4; ++rt) {
        const int t = rt * 256 + wg;                    // row-tile: rows t*64..t*64+63
        stage_xb(x, xb, t, tid);
        __syncthreads();

        f32x4 acc[4][4];
        // ---- S1 = x @ Sw^T + bs (raw) -> sbuf ----
        ZERO_ACC(acc);
        mmx16(acc, ws + WS_XT + 5 * 65536, xb, lane, wv);
        #pragma unroll
        for (int cf = 0; cf < 4; ++cf) {
            int col = (wv << 6) + (cf << 4) + c15;
            float b = BS[col];
            #pragma unroll
            for (int rf = 0; rf < 4; ++rf)
                #pragma unroll
                for (int r = 0; r < 4; ++r) {
                    int row = (rf << 4) + (h << 2) + r;
                    *(unsigned short*)(sbuf + swoff(row, col)) = f2bf(acc[rf][cf][r] + b);
                }
        }
        __syncthreads();

        // ---- G = tanh(ux_g + S1@Wg^T + bg) -> gslot (nt, per-thread packed) ----
        ZERO_ACC(acc);
        mmx16(acc, ws + WS_XT + 3 * 65536, xb, lane, wv);
        mms16(acc, ws + WS_WG, sbuf, lane, wv);
        {
            unsigned int pk[32];
            #pragma unroll
            for (int cf = 0; cf < 4; ++cf) {
                int col = (wv << 6) + (cf << 4) + c15;
                float b = BG[col];
                #pragma unroll
                for (int rf = 0; rf < 4; ++rf) {
                    float v[4];
                    #pragma unroll
                    for (int r = 0; r < 4; ++r) v[r] = fast_tanh(acc[rf][cf][r] + b);
                    pk[(rf * 4 + cf) * 2 + 0] = (unsigned int)f2bf(v[0]) | ((unsigned int)f2bf(v[1]) << 16);
                    pk[(rf * 4 + cf) * 2 + 1] = (unsigned int)f2bf(v[2]) | ((unsigned int)f2bf(v[3]) << 16);
                }
            }
            #pragma unroll
            for (int w = 0; w < 8; ++w) {
                u32x4 q = { pk[w * 4], pk[w * 4 + 1], pk[w * 4 + 2], pk[w * 4 + 3] };
                nts4(gslot + w * 16384 + tid * 16, q);
            }
        }
        // (no LDS writes since S1 -> no barrier needed before Z's reads)

        // ---- 4-layer recurrence, S resident in sbuf ----
        #pragma clang loop unroll(disable)
        for (int L = 0; L < 4; ++L) {
            // Z pass (Wz): ZS -> zslot (nt), freeing registers for R/H
            ZERO_ACC(acc);
            mmx16(acc, ws + WS_XT + 0 * 65536, xb, lane, wv);
            mms16(acc, ws + WS_WZ, sbuf, lane, wv);
            {
                unsigned int pk[32];
                #pragma unroll
                for (int cf = 0; cf < 4; ++cf) {
                    int col = (wv << 6) + (cf << 4) + c15;
                    float bzl = BZ[col];
                    #pragma unroll
                    for (int rf = 0; rf < 4; ++rf) {
                        float v[4];
                        #pragma unroll
                        for (int r = 0; r < 4; ++r) {
                            int row = (rf << 4) + (h << 2) + r;
                            float z = fast_tanh(acc[rf][cf][r] + bzl);
                            v[r] = z * bf2f(*(const unsigned short*)(sbuf + swoff(row, col)));
                        }
                        pk[(rf * 4 + cf) * 2 + 0] = (unsigned int)f2bf(v[0]) | ((unsigned int)f2bf(v[1]) << 16);
                        pk[(rf * 4 + cf) * 2 + 1] = (unsigned int)f2bf(v[2]) | ((unsigned int)f2bf(v[3]) << 16);
                    }
                }
                #pragma unroll
                for (int w = 0; w < 8; ++w) {
                    u32x4 q = { pk[w * 4], pk[w * 4 + 1], pk[w * 4 + 2], pk[w * 4 + 3] };
                    nts4(zslot + w * 16384 + tid * 16, q);
                }
            }

            // R pass (Wg): srp (transient) -> SR into sbuf in place
            ZERO_ACC(acc);
            mmx16(acc, ws + WS_XT + 1 * 65536, xb, lane, wv);
            mms16(acc, ws + WS_WG, sbuf, lane, wv);
            {
                unsigned int srp[32];
                #pragma unroll
                for (int cf = 0; cf < 4; ++cf) {
                    int col = (wv << 6) + (cf << 4) + c15;
                    float brl = BR[col];
                    #pragma unroll
                    for (int rf = 0; rf < 4; ++rf) {
                        float v[4];
                        #pragma unroll
                        for (int r = 0; r < 4; ++r) {
                            int row = (rf << 4) + (h << 2) + r;
                            float rv = fast_tanh(acc[rf][cf][r] + brl);
                            v[r] = rv * bf2f(*(const unsigned short*)(sbuf + swoff(row, col)));
                        }
                        srp[(rf * 4 + cf) * 2 + 0] = (unsigned int)f2bf(v[0]) | ((unsigned int)f2bf(v[1]) << 16);
                        srp[(rf * 4 + cf) * 2 + 1] = (unsigned int)f2bf(v[2]) | ((unsigned int)f2bf(v[3]) << 16);
                    }
                }
                __syncthreads();   // all S reads (Z + R passes) complete
                #pragma unroll
                for (int cf = 0; cf < 4; ++cf) {
                    int col = (wv << 6) + (cf << 4) + c15;
                    #pragma unroll
                    for (int rf = 0; rf < 4; ++rf)
                        #pragma unroll
                        for (int r = 0; r < 4; ++r) {
                            int row = (rf << 4) + (h << 2) + r;
                            unsigned short u = (unsigned short)((srp[(rf * 4 + cf) * 2 + (r >> 1)] >> ((r & 1) * 16)) & 0xffff);
                            *(unsigned short*)(sbuf + swoff(row, col)) = u;
                        }
                }
            }
            __syncthreads();   // SR ready

            // H pass (Wg, same table as R)
            ZERO_ACC(acc);
            mmx16(acc, ws + WS_XT + 2 * 65536, xb, lane, wv);
            mms16(acc, ws + WS_WG, sbuf, lane, wv);
            __syncthreads();   // all SR reads done before newS writes

            if (L < 3) {
                #pragma unroll
                for (int w = 0; w < 8; ++w) {
                    u32x4 g4 = ntl4(gslot + w * 16384 + tid * 16);
                    u32x4 z4 = ntl4(zslot + w * 16384 + tid * 16);
                    #pragma unroll
                    for (int jj = 0; jj < 2; ++jj) {
                        int rfcf = w * 2 + jj;
                        int rf = rfcf >> 2, cf = rfcf & 3;
                        int col = (wv << 6) + (cf << 4) + c15;
                        float bhl = BH[col];
                        #pragma unroll
                        for (int r = 0; r < 4; ++r) {
                            int row = (rf << 4) + (h << 2) + r;
                            float g  = bf2f((unsigned short)((g4[jj * 2 + (r >> 1)] >> ((r & 1) * 16)) & 0xffff));
                            float zs = bf2f((unsigned short)((z4[jj * 2 + (r >> 1)] >> ((r & 1) * 16)) & 0xffff));
                            float hv = fast_tanh(acc[rf][cf][r] + bhl);
                            float o  = (1.0f - g) * hv + zs;
                            *(unsigned short*)(sbuf + swoff(row, col)) = f2bf(fast_tanh(o));
                        }
                    }
                }
                __syncthreads();   // newS visible for next layer
            } else {
                float po[16];
                #pragma unroll
                for (int i = 0; i < 16; ++i) po[i] = 0.0f;
                #pragma unroll
                for (int w = 0; w < 8; ++w) {
                    u32x4 g4 = ntl4(gslot + w * 16384 + tid * 16);
                    u32x4 z4 = ntl4(zslot + w * 16384 + tid * 16);
                    #pragma unroll
                    for (int jj = 0; jj < 2; ++jj) {
                        int rfcf = w * 2 + jj;
                        int rf = rfcf >> 2, cf = rfcf & 3;
                        int col = (wv << 6) + (cf << 4) + c15;
                        float bhl = BH[col];
                        float oww = ow[col];
                        #pragma unroll
                        for (int r = 0; r < 4; ++r) {
                            float g  = bf2f((unsigned short)((g4[jj * 2 + (r >> 1)] >> ((r & 1) * 16)) & 0xffff));
                            float zs = bf2f((unsigned short)((z4[jj * 2 + (r >> 1)] >> ((r & 1) * 16)) & 0xffff));
                            float hv = fast_tanh(acc[rf][cf][r] + bhl);
                            po[(rf << 2) + r] += ((1.0f - g) * hv + zs) * oww;
                        }
                    }
                }
                #pragma unroll
                for (int off = 1; off < 16; off <<= 1)
                    #pragma unroll
                    for (int i = 0; i < 16; ++i) po[i] += __shfl_xor(po[i], off);
                if (c15 == 0) {
                    #pragma unroll
                    for (int rf = 0; rf < 4; ++rf)
                        #pragma unroll
                        for (int r = 0; r < 4; ++r)
                            red[wv * 64 + (rf << 4) + (h << 2) + r] = po[(rf << 2) + r];
                }
                __syncthreads();
                if (tid < 64) {
                    float s = ob[0];
                    #pragma unroll
                    for (int w = 0; w < 16; ++w) s += red[w * 64 + tid];
                    outp[t * 64 + tid] = s;
                }
                __syncthreads();   // red/sbuf free for next row-tile
            }
        }
    }
}

// ================= FALLBACK PATH: round-1 fused kernel (proven) =================

static __device__ __forceinline__ void mm_x(f32x4 acc[2][8], const char* __restrict__ xtab,
                                            const unsigned short* __restrict__ xb,
                                            int lane, int wv) {
    const int c15 = lane & 15, h = lane >> 4;
    bf16x8 a0 = *(const bf16x8*)(xb + c15 * 48 + h * 8);
    bf16x8 a1 = *(const bf16x8*)(xb + (c15 + 16) * 48 + h * 8);
    #pragma unroll
    for (int cf = 0; cf < 8; ++cf) {
        bf16x8 b = *(const bf16x8*)(xtab + ((wv * 8 + cf) << 10) + lane * 16);
        acc[0][cf] = MFMA16(a0, b, acc[0][cf], 0, 0, 0);
        acc[1][cf] = MFMA16(a1, b, acc[1][cf], 0, 0, 0);
    }
}

static __device__ __forceinline__ void mm_s(f32x4 acc[2][8], const char* __restrict__ stab,
                                            const char* __restrict__ sb, int lane, int wv) {
    const int c15 = lane & 15, h = lane >> 4;
    #pragma unroll 2
    for (int ks = 0; ks < 32; ++ks) {
        const char* bp = stab + ((size_t)(ks * 64 + wv * 8) << 10) + lane * 16;
        bf16x8 b[8];
        #pragma unroll
        for (int cf = 0; cf < 8; ++cf) b[cf] = *(const bf16x8*)(bp + (cf << 10));
        bf16x8 a0 = *(const bf16x8*)(sb + swoff(c15,      (ks << 5) + (h << 3)));
        bf16x8 a1 = *(const bf16x8*)(sb + swoff(c15 + 16, (ks << 5) + (h << 3)));
        #pragma unroll
        for (int cf = 0; cf < 8; ++cf) {
            acc[0][cf] = MFMA16(a0, b[cf], acc[0][cf], 0, 0, 0);
            acc[1][cf] = MFMA16(a1, b[cf], acc[1][cf], 0, 0, 0);
        }
    }
}

__global__ __launch_bounds__(512, 2)
void dgm_main(const float* __restrict__ x, const float* __restrict__ out_w,
              const float* __restrict__ out_b, const char* __restrict__ ws,
              float* __restrict__ out) {
    extern __shared__ char lds[];
    char* sbuf0 = lds;
    char* sbuf1 = lds + 65536;
    unsigned short* xb = (unsigned short*)(lds + 131072);
    float* red = (float*)(lds + 131072 + 3072);

    const int tid = threadIdx.x, lane = tid & 63, wv = tid >> 6;
    const int c15 = lane & 15, h = lane >> 4;
    const int t = blockIdx.x;

    const char* WZ = ws + WS_WZ;
    const char* WG = ws + WS_WG;
    const char* XT = ws + WS_XT;
    const float* BZ = (const float*)(ws + WS_BIAS);
    const float* BR = BZ + 1024;
    const float* BH = BZ + 2048;
    const float* BG = BZ + 3072;
    const float* BS = BZ + 4096;

    for (int i = tid; i < 32 * 48; i += 512) {
        int r_ = i / 48, c_ = i % 48;
        float v = (c_ < 16) ? x[(t * 32 + r_) * 16 + c_] : 0.0f;
        xb[r_ * 48 + c_] = f2bf(v);
    }
    __syncthreads();

    f32x4 acc[2][8];
    unsigned int g1m[2][8][2];
    unsigned int zs[2][8][2];
    float po[8];
    #pragma unroll
    for (int i = 0; i < 8; ++i) po[i] = 0.0f;

    #pragma unroll
    for (int rf = 0; rf < 2; ++rf)
        #pragma unroll
        for (int cf = 0; cf < 8; ++cf) acc[rf][cf] = (f32x4)0.0f;
    mm_x(acc, XT + 5 * 65536, xb, lane, wv);
    #pragma unroll
    for (int cf = 0; cf < 8; ++cf) {
        int col = (wv << 7) + (cf << 4) + c15;
        float b = BS[col];
        #pragma unroll
        for (int rf = 0; rf < 2; ++rf)
            #pragma unroll
            for (int r = 0; r < 4; ++r) {
                int row = (rf << 4) + (h << 2) + r;
                *(unsigned short*)(sbuf0 + swoff(row, col)) = f2bf(acc[rf][cf][r] + b);
            }
    }
    __syncthreads();

    {
        #pragma unroll
        for (int rf = 0; rf < 2; ++rf)
            #pragma unroll
            for (int cf = 0; cf < 8; ++cf) acc[rf][cf] = (f32x4)0.0f;
        mm_x(acc, XT + 3 * 65536, xb, lane, wv);
        mm_s(acc, WG, sbuf0, lane, wv);
        unsigned int wgx[2][8][2];
        #pragma unroll
        for (int rf = 0; rf < 2; ++rf)
            #pragma unroll
            for (int cf = 0; cf < 8; ++cf) {
                wgx[rf][cf][0] = (unsigned int)f2bf(acc[rf][cf][0]) |
                                 ((unsigned int)f2bf(acc[rf][cf][1]) << 16);
                wgx[rf][cf][1] = (unsigned int)f2bf(acc[rf][cf][2]) |
                                 ((unsigned int)f2bf(acc[rf][cf][3]) << 16);
            }
        #pragma unroll
        for (int rf = 0; rf < 2; ++rf)
            #pragma unroll
            for (int cf = 0; cf < 8; ++cf) acc[rf][cf] = (f32x4)0.0f;
        mm_x(acc, XT + 4 * 65536, xb, lane, wv);
        #pragma unroll
        for (int cf = 0; cf < 8; ++cf) {
            int col = (wv << 7) + (cf << 4) + c15;
            float brl = BR[col], bgl = BG[col];
            #pragma unroll
            for (int rf = 0; rf < 2; ++rf) {
                float g1v[4];
                #pragma unroll
                for (int r = 0; r < 4; ++r) {
                    int row = (rf << 4) + (h << 2) + r;
                    float wgv = bf2f((unsigned short)((wgx[rf][cf][r >> 1] >> ((r & 1) * 16)) & 0xffff));
                    float rv = fast_tanh(wgv + acc[rf][cf][r] + brl);
                    float s1 = bf2f(*(const unsigned short*)(sbuf0 + swoff(row, col)));
                    *(unsigned short*)(sbuf1 + swoff(row, col)) = f2bf(s1 * rv);
                    g1v[r] = 1.0f - fast_tanh(wgv + bgl);
                }
                g1m[rf][cf][0] = (unsigned int)f2bf(g1v[0]) | ((unsigned int)f2bf(g1v[1]) << 16);
                g1m[rf][cf][1] = (unsigned int)f2bf(g1v[2]) | ((unsigned int)f2bf(g1v[3]) << 16);
            }
        }
    }
    __syncthreads();

    char* cur = sbuf0;
    char* oth = sbuf1;
    #pragma clang loop unroll(disable)
    for (int L = 0; L < 4; ++L) {
        #pragma unroll
        for (int rf = 0; rf < 2; ++rf)
            #pragma unroll
            for (int cf = 0; cf < 8; ++cf) acc[rf][cf] = (f32x4)0.0f;
        mm_x(acc, XT + 0 * 65536, xb, lane, wv);
        mm_s(acc, WZ, cur, lane, wv);
        #pragma unroll
        for (int cf = 0; cf < 8; ++cf) {
            int col = (wv << 7) + (cf << 4) + c15;
            float bzl = BZ[col];
            #pragma unroll
            for (int rf = 0; rf < 2; ++rf) {
                float zv[4];
                #pragma unroll
                for (int r = 0; r < 4; ++r) {
                    int row = (rf << 4) + (h << 2) + r;
                    float z = fast_tanh(acc[rf][cf][r] + bzl);
                    float s = bf2f(*(const unsigned short*)(cur + swoff(row, col)));
                    zv[r] = z * s;
                }
                zs[rf][cf][0] = (unsigned int)f2bf(zv[0]) | ((unsigned int)f2bf(zv[1]) << 16);
                zs[rf][cf][1] = (unsigned int)f2bf(zv[2]) | ((unsigned int)f2bf(zv[3]) << 16);
            }
        }
        if (L > 0) {
            #pragma unroll
            for (int rf = 0; rf < 2; ++rf)
                #pragma unroll
                for (int cf = 0; cf < 8; ++cf) acc[rf][cf] = (f32x4)0.0f;
            mm_x(acc, XT + 1 * 65536, xb, lane, wv);
            mm_s(acc, WG, cur, lane, wv);
            #pragma unroll
            for (int cf = 0; cf < 8; ++cf) {
                int col = (wv << 7) + (cf << 4) + c15;
                float brl = BR[col];
                #pragma unroll
                for (int rf = 0; rf < 2; ++rf)
                    #pragma unroll
                    for (int r = 0; r < 4; ++r) {
                        int row = (rf << 4) + (h << 2) + r;
                        float rv = fast_tanh(acc[rf][cf][r] + brl);
                        float s = bf2f(*(const unsigned short*)(cur + swoff(row, col)));
                        *(unsigned short*)(oth + swoff(row, col)) = f2bf(s * rv);
                    }
            }
        }
        __syncthreads();
        #pragma unroll
        for (int rf = 0; rf < 2; ++rf)
            #pragma unroll
            for (int cf = 0; cf < 8; ++cf) acc[rf][cf] = (f32x4)0.0f;
        mm_x(acc, XT + 2 * 65536, xb, lane, wv);
        mm_s(acc, WG, oth, lane, wv);
        __syncthreads();
        if (L < 3) {
            #pragma unroll
            for (int cf = 0; cf < 8; ++cf) {
                int col = (wv << 7) + (cf << 4) + c15;
                float bhl = BH[col];
                #pragma unroll
                for (int rf = 0; rf < 2; ++rf)
                    #pragma unroll
                    for (int r = 0; r < 4; ++r) {
                        int row = (rf << 4) + (h << 2) + r;
                        float hv = fast_tanh(acc[rf][cf][r] + bhl);
                        float g1 = bf2f((unsigned short)((g1m[rf][cf][r >> 1] >> ((r & 1) * 16)) & 0xffff));
                        float zsv = bf2f((unsigned short)((zs[rf][cf][r >> 1] >> ((r & 1) * 16)) & 0xffff));
                        float o = g1 * hv + zsv;
                        *(unsigned short*)(oth + swoff(row, col)) = f2bf(fast_tanh(o));
                    }
            }
        } else {
            #pragma unroll
            for (int cf = 0; cf < 8; ++cf) {
                int col = (wv << 7) + (cf << 4) + c15;
                float bhl = BH[col];
                float oww = out_w[col];
                #pragma unroll
                for (int rf = 0; rf < 2; ++rf)
                    #pragma unroll
                    for (int r = 0; r < 4; ++r) {
                        float hv = fast_tanh(acc[rf][cf][r] + bhl);
                        float g1 = bf2f((unsigned short)((g1m[rf][cf][r >> 1] >> ((r & 1) * 16)) & 0xffff));
                        float zsv = bf2f((unsigned short)((zs[rf][cf][r >> 1] >> ((r & 1) * 16)) & 0xffff));
                        po[(rf << 2) + r] += (g1 * hv + zsv) * oww;
                    }
            }
        }
        __syncthreads();
        char* tmp = cur; cur = oth; oth = tmp;
    }

    #pragma unroll
    for (int off = 1; off < 16; off <<= 1)
        #pragma unroll
        for (int i = 0; i < 8; ++i) po[i] += __shfl_xor(po[i], off);
    if (c15 == 0) {
        #pragma unroll
        for (int rf = 0; rf < 2; ++rf)
            #pragma unroll
            for (int r = 0; r < 4; ++r)
                red[wv * 32 + (rf << 4) + (h << 2) + r] = po[(rf << 2) + r];
    }
    __syncthreads();
    if (tid < 32) {
        float s = out_b[0];
        #pragma unroll
        for (int w = 0; w < 8; ++w) s += red[w * 32 + tid];
        out[t * 32 + tid] = s;
    }
}

// ---------------- host ----------------
extern "C" void kernel_launch(void* const* d_in, const int* in_sizes, int n_in,
                              void* d_out, int out_size, void* d_ws, size_t ws_size,
                              hipStream_t stream) {
    (void)in_sizes; (void)n_in; (void)out_size;
    const float* x    = (const float*)d_in[0];
    const float* Sw_w = (const float*)d_in[1];
    const float* Sw_b = (const float*)d_in[2];
    const float* Uz_w = (const float*)d_in[3];
    const float* Uz_b = (const float*)d_in[4];
    const float* Wz_w = (const float*)d_in[5];
    const float* Wz_b = (const float*)d_in[6];
    const float* Ug_w = (const float*)d_in[7];
    const float* Ug_b = (const float*)d_in[8];
    const float* Wg_w = (const float*)d_in[9];
    const float* Wg_b = (const float*)d_in[10];
    const float* Ur_w = (const float*)d_in[11];
    const float* Ur_b = (const float*)d_in[12];
    const float* Uh_w = (const float*)d_in[13];
    const float* Uh_b = (const float*)d_in[14];
    const float* ow   = (const float*)d_in[15];
    const float* ob   = (const float*)d_in[16];
    char* ws = (char*)d_ws;

    prep_big<<<4096, 64, 0, stream>>>(Wz_w, Wg_w, ws);
    prep_x<<<384, 64, 0, stream>>>(Uz_w, Ur_w, Uh_w, Ug_w, Sw_w, ws + WS_XT);
    prep_bias<<<4, 256, 0, stream>>>(Uz_b, Wz_b, Ur_b, Uh_b, Ug_b, Wg_b, Sw_b,
                                     (float*)(ws + WS_BIAS));

    if (ws_size >= WS_NEED2) {
        const int LM = 131072 + 4096 + 4096;   // 136 KiB
        hipFuncSetAttribute(reinterpret_cast<const void*>(mega),
                            hipFuncAttributeMaxDynamicSharedMemorySize, LM);
        mega<<<256, 1024, LM, stream>>>(x, ws, ow, ob, (float*)d_out,
                                        ws + WS_GB, ws + WS_ZB);
    } else {
        const int ldsBytes = 131072 + 3072 + 1024;
        hipFuncSetAttribute(reinterpret_cast<const void*>(dgm_main),
                            hipFuncAttributeMaxDynamicSharedMemorySize, ldsBytes);
        dgm_main<<<65536 / 32, 512, ldsBytes, stream>>>(x, ow, ob, ws, (float*)d_out);
    }
}